// Round 6
// baseline (180.728 us; speedup 1.0000x reference)
//
#include <hip/hip_runtime.h>
#include <cmath>

typedef unsigned short u16;
typedef unsigned int   u32;
typedef __attribute__((ext_vector_type(8)))  short short8;
typedef __attribute__((ext_vector_type(4)))  float f32x4;
typedef __attribute__((ext_vector_type(16))) float f32x16;

constexpr int BT    = 32;
constexpr int NTOK  = 512;
constexpr int DIM   = 256;
constexpr int HID   = 256;
constexpr int M_ROWS = BT * NTOK;             // 16384
constexpr int HM     = M_ROWS * 32;           // per-head elems in head-major QKV
constexpr size_t TENS = (size_t)M_ROWS * HID;
constexpr float LAMBDA_INIT  = 0.35550906759096927f;
constexpr float ONE_MINUS_LI = 0.6444909324090307f;
constexpr float LN_EPS = 1e-5f;
constexpr float QSCALE = 0.36067376022224085f;  // 0.25 * log2(e): folded into Q

#define MFMA16(a, b, c) __builtin_amdgcn_mfma_f32_16x16x32_bf16((a), (b), (c), 0, 0, 0)
#define MFMA32(a, b, c) __builtin_amdgcn_mfma_f32_32x32x16_bf16((a), (b), (c), 0, 0, 0)

__device__ __forceinline__ u16 f2bf(float f) {   // RNE
    u32 u = __float_as_uint(f);
    return (u16)((u + 0x7FFFu + ((u >> 16) & 1u)) >> 16);
}

__device__ __forceinline__ float fexp2(float x) {
#if defined(__has_builtin) && __has_builtin(__builtin_amdgcn_exp2f)
    return __builtin_amdgcn_exp2f(x);
#else
    return exp2f(x);
#endif
}

// pack two f32 -> two bf16 (truncate) in one dword: a in low half
__device__ __forceinline__ u32 pack_trunc(float a, float b) {
    return __builtin_amdgcn_perm(__float_as_uint(b), __float_as_uint(a), 0x07060302u);
}

// ---------------------------------------------------------------------------
// prep_w: transpose + convert W (f32 [k][n]) -> Wt (bf16 [n][k]), 3 matrices
// ---------------------------------------------------------------------------
__global__ __launch_bounds__(256) void prep_w(const float* __restrict__ Wq,
                                              const float* __restrict__ Wk,
                                              const float* __restrict__ Wv,
                                              u16* __restrict__ Wt) {
    const float* W = (blockIdx.z == 0) ? Wq : (blockIdx.z == 1) ? Wk : Wv;
    u16* dst = Wt + (size_t)blockIdx.z * 65536;
    __shared__ float T[64][65];
    const int k0 = blockIdx.x * 64, n0 = blockIdx.y * 64;
    const int tr = threadIdx.x >> 4;
    const int tc = threadIdx.x & 15;
    #pragma unroll
    for (int i = 0; i < 4; ++i) {
        int row = tr + i * 16;
        float4 v = *(const float4*)&W[(size_t)(k0 + row) * HID + n0 + tc * 4];
        T[row][tc * 4 + 0] = v.x; T[row][tc * 4 + 1] = v.y;
        T[row][tc * 4 + 2] = v.z; T[row][tc * 4 + 3] = v.w;
    }
    __syncthreads();
    #pragma unroll
    for (int i = 0; i < 4; ++i) {
        int n = tr + i * 16;
        int k4 = tc * 4;
        uint2 pk;
        pk.x = (u32)f2bf(T[k4 + 0][n]) | ((u32)f2bf(T[k4 + 1][n]) << 16);
        pk.y = (u32)f2bf(T[k4 + 2][n]) | ((u32)f2bf(T[k4 + 3][n]) << 16);
        *(uint2*)&dst[(size_t)(n0 + n) * DIM + k0 + k4] = pk;
    }
}

// ---------------------------------------------------------------------------
// proj: fused QKV GEMM, register-prefetch pipelined. Tile 64x64, BK=64,
// 4 waves each 32x32, operand-swapped MFMA (D.row = weight-col n).
// Epilogue: bf16-pack into per-wave private LDS tile [32m][36n], read back
// row-contiguous, store 1024B-contiguous dwordx4 (full 128B lines -> no
// partial-line write amplification). Head-major output; Q pre-scaled.
// ---------------------------------------------------------------------------
__global__ __launch_bounds__(256, 4) void proj_kernel(
    const float* __restrict__ x, const u16* __restrict__ Wt,
    u16* __restrict__ Qh, u16* __restrict__ Kh, u16* __restrict__ Vh)
{
    __shared__ u16 As[64 * 72];      // [m][k], stride 72; reused as epilogue buf
    __shared__ u16 Bs[3][64 * 72];   // [n][k] per z

    const int tid  = threadIdx.x;
    const int n0   = blockIdx.x * 64;
    const int m0   = blockIdx.y * 64;
    const int lane = tid & 63;
    const int wv   = tid >> 6;
    const int q16  = lane & 15;
    const int quad = lane >> 4;
    const int mw   = (wv >> 1) * 32;
    const int nw   = (wv & 1) * 32;

    const int sr = tid >> 2;          // 0..63 staging row
    const int sc = (tid & 3) * 16;    // 0,16,32,48 (u16 elems within 64-k)

    f32x4 acc[3][4];
    #pragma unroll
    for (int z = 0; z < 3; ++z)
        #pragma unroll
        for (int t = 0; t < 4; ++t)
            acc[z][t] = (f32x4){0.f, 0.f, 0.f, 0.f};

    // prefetch registers
    float4 ga[4];
    uint4  gb[3][2];
    {
        const float4* xs = (const float4*)&x[(size_t)(m0 + sr) * DIM + sc];
        ga[0] = xs[0]; ga[1] = xs[1]; ga[2] = xs[2]; ga[3] = xs[3];
        #pragma unroll
        for (int z = 0; z < 3; ++z) {
            const uint4* ws4 = (const uint4*)&Wt[(size_t)z * 65536 + (size_t)(n0 + sr) * DIM + sc];
            gb[z][0] = ws4[0]; gb[z][1] = ws4[1];
        }
    }

    for (int it = 0; it < 4; ++it) {
        {
            uint4 o0, o1;
            o0.x = (u32)f2bf(ga[0].x) | ((u32)f2bf(ga[0].y) << 16);
            o0.y = (u32)f2bf(ga[0].z) | ((u32)f2bf(ga[0].w) << 16);
            o0.z = (u32)f2bf(ga[1].x) | ((u32)f2bf(ga[1].y) << 16);
            o0.w = (u32)f2bf(ga[1].z) | ((u32)f2bf(ga[1].w) << 16);
            o1.x = (u32)f2bf(ga[2].x) | ((u32)f2bf(ga[2].y) << 16);
            o1.y = (u32)f2bf(ga[2].z) | ((u32)f2bf(ga[2].w) << 16);
            o1.z = (u32)f2bf(ga[3].x) | ((u32)f2bf(ga[3].y) << 16);
            o1.w = (u32)f2bf(ga[3].z) | ((u32)f2bf(ga[3].w) << 16);
            *(uint4*)&As[sr * 72 + sc]     = o0;
            *(uint4*)&As[sr * 72 + sc + 8] = o1;
            #pragma unroll
            for (int z = 0; z < 3; ++z) {
                *(uint4*)&Bs[z][sr * 72 + sc]     = gb[z][0];
                *(uint4*)&Bs[z][sr * 72 + sc + 8] = gb[z][1];
            }
        }
        __syncthreads();

        if (it < 3) {   // prefetch next K-tile (overlaps MFMA below)
            const int kk = (it + 1) * 64;
            const float4* xs = (const float4*)&x[(size_t)(m0 + sr) * DIM + kk + sc];
            ga[0] = xs[0]; ga[1] = xs[1]; ga[2] = xs[2]; ga[3] = xs[3];
            #pragma unroll
            for (int z = 0; z < 3; ++z) {
                const uint4* ws4 = (const uint4*)&Wt[(size_t)z * 65536 + (size_t)(n0 + sr) * DIM + kk + sc];
                gb[z][0] = ws4[0]; gb[z][1] = ws4[1];
            }
        }

        #pragma unroll
        for (int kc = 0; kc < 2; ++kc) {
            short8 a0 = *(const short8*)&As[(mw +      q16) * 72 + kc * 32 + quad * 8];
            short8 a1 = *(const short8*)&As[(mw + 16 + q16) * 72 + kc * 32 + quad * 8];
            #pragma unroll
            for (int z = 0; z < 3; ++z) {
                short8 b0 = *(const short8*)&Bs[z][(nw +      q16) * 72 + kc * 32 + quad * 8];
                short8 b1 = *(const short8*)&Bs[z][(nw + 16 + q16) * 72 + kc * 32 + quad * 8];
                acc[z][0] = MFMA16(b0, a0, acc[z][0]);   // m-half 0, n-half 0
                acc[z][1] = MFMA16(b1, a0, acc[z][1]);   // m-half 0, n-half 1
                acc[z][2] = MFMA16(b0, a1, acc[z][2]);   // m-half 1, n-half 0
                acc[z][3] = MFMA16(b1, a1, acc[z][3]);   // m-half 1, n-half 1
            }
        }
        __syncthreads();
    }

    // ---- epilogue: LDS rearrange -> full-line coalesced stores ----
    // acc[z][t][r]: m = mw + (t>>1)*16 + q16, n = nw + (t&1)*16 + quad*4 + r
    u16* Ep = &As[wv * 1152];   // per-wave [32m][36n] bf16 tile (2304 B)
    const int hcol = (n0 + nw) >> 5;
    #pragma unroll
    for (int z = 0; z < 3; ++z) {
        const float s = (z == 0) ? QSCALE : 1.0f;
        #pragma unroll
        for (int t = 0; t < 4; ++t) {
            uint2 w;
            w.x = (u32)f2bf(acc[z][t][0] * s) | ((u32)f2bf(acc[z][t][1] * s) << 16);
            w.y = (u32)f2bf(acc[z][t][2] * s) | ((u32)f2bf(acc[z][t][3] * s) << 16);
            *(uint2*)&Ep[((t >> 1) * 16 + q16) * 36 + (t & 1) * 16 + quad * 4] = w;
        }
        u16* C = (z == 0) ? Qh : (z == 1) ? Kh : Vh;
        u16* gbase = C + (size_t)hcol * HM + (size_t)(m0 + mw) * 32;
        #pragma unroll
        for (int i = 0; i < 2; ++i) {
            const int lrow = i * 16 + (lane >> 2);
            uint4 v = *(const uint4*)&Ep[lrow * 36 + (lane & 3) * 8];
            *(uint4*)&gbase[(size_t)lrow * 32 + (lane & 3) * 8] = v;
        }
    }
}

// ---------------------------------------------------------------------------
// attn: 32x32x16 MFMA attention, register-resident P (no LDS round-trip).
// grid (4, 8, 32); 256 threads (4 waves), 32 q/wave, keys in 2 chunks of 256.
// QK: S^T = MFMA32(A=K, B=Q): D col=lane&31=q, row=(r&3)+8*(r>>2)+4*hi=key.
// P transform: exp in regs -> pack_trunc -> 4x shfl_xor(32) + cndmask
// assembles PV A-fragments in-register (lane already owns its q row).
// K staged fragment-ordered (lane-linear contiguous 1KB LDS reads).
// LDS 33.3 KB -> 4 blocks/CU.
// ---------------------------------------------------------------------------
__global__ __launch_bounds__(256, 4) void attn_kernel(
    const u16* __restrict__ Qh, const u16* __restrict__ Kh, const u16* __restrict__ Vh,
    const float* __restrict__ lq1, const float* __restrict__ lk1,
    const float* __restrict__ lq2, const float* __restrict__ lk2,
    const float* __restrict__ gamma, const float* __restrict__ beta,
    float* __restrict__ out)
{
    __shared__ u16 Ks[256 * 64];    // frag-order: [tile][oct][key&31] 16B units
    __shared__ u16 Vts[32 * 264];   // [dim][key0..255], stride 264

    const int qh  = blockIdx.x;   // 0..3 (128 q rows each)
    const int h   = blockIdx.y;   // 0..7
    const int bt  = blockIdx.z;   // 0..31
    const int tid = threadIdx.x;
    const int lane = tid & 63;
    const int wv   = tid >> 6;
    const int l31  = lane & 31;
    const int hi   = lane >> 5;

    // lambda (uniform scalar path)
    float sa = 0.f, sb = 0.f;
    #pragma unroll
    for (int d = 0; d < 16; ++d) { sa += lq1[d] * lk1[d]; sb += lq2[d] * lk2[d]; }
    const float lam = __expf(sa) - __expf(sb) + LAMBDA_INIT;

    // persistent Q B-fragments: n=q=lane&31, k=(lane>>5)*8+j
    const int qbase = bt * NTOK + qh * 128 + wv * 32;
    const size_t hbase = (size_t)h * HM;
    const u16* qrowp = Qh + hbase + (size_t)(qbase + l31) * 32 + hi * 8;
    const short8 B1 = *(const short8*)qrowp;          // Q1 dims 0..15
    const short8 B2 = *(const short8*)(qrowp + 16);   // Q2 dims 16..31

    const f32x16 z16 = {0.f,0.f,0.f,0.f,0.f,0.f,0.f,0.f,0.f,0.f,0.f,0.f,0.f,0.f,0.f,0.f};
    f32x16 O1 = z16, O2 = z16;
    float l1 = 0.f, l2 = 0.f;

    for (int chunk = 0; chunk < 2; ++chunk) {
        if (chunk) __syncthreads();   // drain previous chunk's LDS reads
        // ---- stage K chunk fragment-ordered: thread -> key = chunk*256+tid ----
        {
            const uint4* src = (const uint4*)(Kh + hbase +
                                (size_t)(bt * NTOK + chunk * 256 + tid) * 32);
            uint4 r0 = src[0], r1 = src[1], r2 = src[2], r3 = src[3];
            u16* d0 = &Ks[((tid >> 5) * 128 + (tid & 31)) * 8];
            *(uint4*)(d0 + 0 * 256) = r0;   // dims 0..7   (oct 0)
            *(uint4*)(d0 + 1 * 256) = r1;   // dims 8..15  (oct 1)
            *(uint4*)(d0 + 2 * 256) = r2;   // dims 16..23 (oct 2)
            *(uint4*)(d0 + 3 * 256) = r3;   // dims 24..31 (oct 3)
        }
        // ---- stage V chunk transposed: threads 0..127, 2 keys each ----
        if (tid < 128) {
            const int j0 = tid * 2;
            const u16* v0 = Vh + hbase + (size_t)(bt * NTOK + chunk * 256 + j0) * 32;
            union U { uint4 q[4]; u32 w[16]; } ra, rb;
            #pragma unroll
            for (int i = 0; i < 4; ++i) {
                ra.q[i] = ((const uint4*)v0)[i];
                rb.q[i] = ((const uint4*)(v0 + 32))[i];
            }
            #pragma unroll
            for (int w = 0; w < 16; ++w) {
                u32 lo  = __builtin_amdgcn_perm(rb.w[w], ra.w[w], 0x05040100u);
                u32 hi2 = __builtin_amdgcn_perm(rb.w[w], ra.w[w], 0x07060302u);
                *(u32*)&Vts[(2 * w)     * 264 + j0] = lo;
                *(u32*)&Vts[(2 * w + 1) * 264 + j0] = hi2;
            }
        }
        __syncthreads();

        for (int kc = 0; kc < 8; ++kc) {   // 32 keys per tile
            const int tb = kc * 1024;      // tile base (u16)
            // K A-frags: lane-linear contiguous reads
            const short8 A1 = *(const short8*)&Ks[tb + lane * 8];          // dims 0..15
            const short8 A2 = *(const short8*)&Ks[tb + 512 + lane * 8];    // dims 16..31
            // V^T B-frags: n=dim=l31, k=key
            const u16* vrow = &Vts[l31 * 264 + kc * 32 + hi * 8];
            const short8 Vt0 = *(const short8*)vrow;          // keys 0..15
            const short8 Vt1 = *(const short8*)(vrow + 16);   // keys 16..31

            const f32x16 S1 = MFMA32(A1, B1, z16);
            const f32x16 S2 = MFMA32(A2, B2, z16);

            #pragma unroll
            for (int ch = 0; ch < 2; ++ch) {
                const f32x16& S = ch ? S2 : S1;
                float e[16];
                #pragma unroll
                for (int j = 0; j < 16; ++j) e[j] = fexp2(S[j]);
                float ls = ((e[0]+e[1])+(e[2]+e[3])) + ((e[4]+e[5])+(e[6]+e[7]))
                         + ((e[8]+e[9])+(e[10]+e[11])) + ((e[12]+e[13])+(e[14]+e[15]));
                if (ch) l2 += ls; else l1 += ls;
                u32 dw[8];
                #pragma unroll
                for (int i = 0; i < 8; ++i) dw[i] = pack_trunc(e[2*i], e[2*i+1]);
                // cross-half exchange: partner needs dw0,1,4,5 (from hi=1's view)
                // send what partner needs; receive what we need.
                u32 s0 = hi ? dw[0] : dw[2];
                u32 s1 = hi ? dw[1] : dw[3];
                u32 s2 = hi ? dw[4] : dw[6];
                u32 s3 = hi ? dw[5] : dw[7];
                u32 r0 = (u32)__shfl_xor((int)s0, 32);
                u32 r1 = (u32)__shfl_xor((int)s1, 32);
                u32 r2 = (u32)__shfl_xor((int)s2, 32);
                u32 r3 = (u32)__shfl_xor((int)s3, 32);
                union { u32 u[4]; short8 s; } f1, f2;
                // frag1 keys 0..15: hi0=[dw0,dw1,r0,r1], hi1=[r0,r1,dw2,dw3]
                f1.u[0] = hi ? r0    : dw[0];
                f1.u[1] = hi ? r1    : dw[1];
                f1.u[2] = hi ? dw[2] : r0;
                f1.u[3] = hi ? dw[3] : r1;
                // frag2 keys 16..31: hi0=[dw4,dw5,r2,r3], hi1=[r2,r3,dw6,dw7]
                f2.u[0] = hi ? r2    : dw[4];
                f2.u[1] = hi ? r3    : dw[5];
                f2.u[2] = hi ? dw[6] : r2;
                f2.u[3] = hi ? dw[7] : r3;
                if (ch) {
                    O2 = MFMA32(f1.s, Vt0, O2);
                    O2 = MFMA32(f2.s, Vt1, O2);
                } else {
                    O1 = MFMA32(f1.s, Vt0, O1);
                    O1 = MFMA32(f2.s, Vt1, O1);
                }
            }
        }
    }

    // ---- epilogue ----
    l1 += __shfl_xor(l1, 32);
    l2 += __shfl_xor(l2, 32);
    const float i1base = 1.0f / l1;   // valid for q = l31
    const float i2base = 1.0f / l2;
    const float g  = gamma[l31];
    const float bc = beta[l31];

    #pragma unroll
    for (int r = 0; r < 16; ++r) {
        const int qloc = (r & 3) + 8 * (r >> 2) + 4 * hi;   // this reg's q row
        const float i1 = __shfl(i1base, qloc);
        const float i2 = __shfl(i2base, qloc);
        float y = O1[r] * i1 - lam * (O2[r] * i2);

        // LayerNorm over 32 dims (dims live in l31 lanes within each 32-half)
        float s  = y;
        float s2 = y * y;
        #pragma unroll
        for (int off = 1; off < 32; off <<= 1) {
            s  += __shfl_xor(s,  off);
            s2 += __shfl_xor(s2, off);
        }
        const float mu   = s * (1.0f / 32.0f);
        const float var  = s2 * (1.0f / 32.0f) - mu * mu;
        const float rstd = rsqrtf(var + LN_EPS);

        const int row = qbase + qloc;
        out[(size_t)row * HID + h * 32 + l31] = ((y - mu) * rstd * g + bc) * ONE_MINUS_LI;
    }
}

// ---------------------------------------------------------------------------
extern "C" void kernel_launch(void* const* d_in, const int* in_sizes, int n_in,
                              void* d_out, int out_size, void* d_ws, size_t ws_size,
                              hipStream_t stream) {
    const float* x   = (const float*)d_in[0];
    const float* Wq  = (const float*)d_in[1];
    const float* Wk  = (const float*)d_in[2];
    const float* Wv  = (const float*)d_in[3];
    const float* lq1 = (const float*)d_in[4];
    const float* lk1 = (const float*)d_in[5];
    const float* lq2 = (const float*)d_in[6];
    const float* lk2 = (const float*)d_in[7];
    const float* gam = (const float*)d_in[8];
    const float* bet = (const float*)d_in[9];
    float* out = (float*)d_out;

    u16* ws = (u16*)d_ws;
    u16* Wt = ws;                 // 3 * 65536
    u16* Qh = Wt + 3 * 65536;     // head-major [8][16384][32]
    u16* Kh = Qh + TENS;
    u16* Vh = Kh + TENS;

    hipLaunchKernelGGL(prep_w, dim3(4, 4, 3), dim3(256), 0, stream, Wq, Wk, Wv, Wt);
    hipLaunchKernelGGL(proj_kernel, dim3(HID / 64, M_ROWS / 64), dim3(256), 0, stream,
                       x, Wt, Qh, Kh, Vh);
    hipLaunchKernelGGL(attn_kernel, dim3(4, 8, 32), dim3(256), 0, stream,
                       Qh, Kh, Vh, lq1, lk1, lq2, lk2, gam, bet, out);
}

// Round 7
// 147.489 us; speedup vs baseline: 1.2254x; 1.2254x over previous
//
#include <hip/hip_runtime.h>
#include <cmath>

typedef unsigned short u16;
typedef unsigned int   u32;
typedef __attribute__((ext_vector_type(8)))  short short8;
typedef __attribute__((ext_vector_type(4)))  float f32x4;
typedef __attribute__((ext_vector_type(16))) float f32x16;

constexpr int BT    = 32;
constexpr int NTOK  = 512;
constexpr int DIM   = 256;
constexpr int HID   = 256;
constexpr float LAMBDA_INIT  = 0.35550906759096927f;
constexpr float ONE_MINUS_LI = 0.6444909324090307f;
constexpr float LN_EPS = 1e-5f;
constexpr float QSCALE = 0.36067376022224085f;  // 0.25 * log2(e): folded into Q

#define MFMA16(a, b, c) __builtin_amdgcn_mfma_f32_16x16x32_bf16((a), (b), (c), 0, 0, 0)
#define MFMA32(a, b, c) __builtin_amdgcn_mfma_f32_32x32x16_bf16((a), (b), (c), 0, 0, 0)

__device__ __forceinline__ u16 f2bf(float f) {   // RNE
    u32 u = __float_as_uint(f);
    return (u16)((u + 0x7FFFu + ((u >> 16) & 1u)) >> 16);
}

__device__ __forceinline__ float fexp2(float x) {
#if defined(__has_builtin) && __has_builtin(__builtin_amdgcn_exp2f)
    return __builtin_amdgcn_exp2f(x);
#else
    return exp2f(x);
#endif
}

// pack two f32 -> two bf16 (truncate) in one dword: a in low half
__device__ __forceinline__ u32 pack_trunc(float a, float b) {
    return __builtin_amdgcn_perm(__float_as_uint(b), __float_as_uint(a), 0x07060302u);
}

// assemble short8 from 8B-aligned LDS via 2x b64
__device__ __forceinline__ short8 ldb64x2(const u16* p) {
    uint2 a = *(const uint2*)p;
    uint2 b = *(const uint2*)(p + 4);
    union { u32 u[4]; short8 s; } x;
    x.u[0] = a.x; x.u[1] = a.y; x.u[2] = b.x; x.u[3] = b.y;
    return x.s;
}

// ---------------------------------------------------------------------------
// prep_w: transpose + convert W (f32 [k][n]) -> Wt (bf16 [n][k]), 3 matrices
// ---------------------------------------------------------------------------
__global__ __launch_bounds__(256) void prep_w(const float* __restrict__ Wq,
                                              const float* __restrict__ Wk,
                                              const float* __restrict__ Wv,
                                              u16* __restrict__ Wt) {
    const float* W = (blockIdx.z == 0) ? Wq : (blockIdx.z == 1) ? Wk : Wv;
    u16* dst = Wt + (size_t)blockIdx.z * 65536;
    __shared__ float T[64][65];
    const int k0 = blockIdx.x * 64, n0 = blockIdx.y * 64;
    const int tr = threadIdx.x >> 4;
    const int tc = threadIdx.x & 15;
    #pragma unroll
    for (int i = 0; i < 4; ++i) {
        int row = tr + i * 16;
        float4 v = *(const float4*)&W[(size_t)(k0 + row) * HID + n0 + tc * 4];
        T[row][tc * 4 + 0] = v.x; T[row][tc * 4 + 1] = v.y;
        T[row][tc * 4 + 2] = v.z; T[row][tc * 4 + 3] = v.w;
    }
    __syncthreads();
    #pragma unroll
    for (int i = 0; i < 4; ++i) {
        int n = tr + i * 16;
        int k4 = tc * 4;
        uint2 pk;
        pk.x = (u32)f2bf(T[k4 + 0][n]) | ((u32)f2bf(T[k4 + 1][n]) << 16);
        pk.y = (u32)f2bf(T[k4 + 2][n]) | ((u32)f2bf(T[k4 + 3][n]) << 16);
        *(uint2*)&dst[(size_t)(n0 + n) * DIM + k0 + k4] = pk;
    }
}

// ---------------------------------------------------------------------------
// fused: per (bt,h) block (grid 32x8, bt fastest -> 8 h-blocks share XCD L2
// for x). 512 threads (8 waves). QKV computed in-block via MFMA32 from
// LDS-staged x; K/V chunk0 -> frag-ordered LDS, chunk1 K/V + all Q -> 64KB
// per-block global scratch (L2-hot). Attention = R3-proven MFMA16 inner loop
// (dual-P per wave, masked-Q K=32), frags hoisted per key-tile. QKV never
// touches HBM as a tensor.
// ---------------------------------------------------------------------------
__global__ __launch_bounds__(512, 2) void fused_kernel(
    const float* __restrict__ x, const u16* __restrict__ Wt,
    u16* __restrict__ gscratch,
    const float* __restrict__ lq1, const float* __restrict__ lk1,
    const float* __restrict__ lq2, const float* __restrict__ lk2,
    const float* __restrict__ gamma, const float* __restrict__ beta,
    float* __restrict__ out)
{
    // LDS: KlsF 16KB frag-ordered K (256 keys), VtF 16KB frag-ordered V^T,
    // XP 20KB = union{ x-stage [256][40] bf16 , per-wave dual-P [16][36] x2 }
    __shared__ u16 KlsF[8192];
    __shared__ u16 VtF[8192];
    __shared__ u16 XP[10240];

    const int bt  = blockIdx.x;   // 0..31
    const int h   = blockIdx.y;   // 0..7
    const int tid = threadIdx.x;
    const int lane = tid & 63;
    const int wv   = tid >> 6;    // 0..7
    const int l31  = lane & 31;
    const int hi   = lane >> 5;
    const int q16  = lane & 15;
    const int quad = lane >> 4;

    u16* gQ = gscratch + (size_t)(bt + 32 * h) * 32768;   // [512 tok][32 dim]
    u16* gK = gQ + 16384;                                 // frag-order chunk1
    u16* gV = gK + 8192;

    // lambda (uniform scalar path)
    float sa = 0.f, sb = 0.f;
    #pragma unroll
    for (int d = 0; d < 16; ++d) { sa += lq1[d] * lk1[d]; sb += lq2[d] * lk2[d]; }
    const float lam = __expf(sa) - __expf(sb) + LAMBDA_INIT;

    const f32x16 z32 = {0.f,0.f,0.f,0.f,0.f,0.f,0.f,0.f,0.f,0.f,0.f,0.f,0.f,0.f,0.f,0.f};

    // =================== Phase 1: QKV generation ===================
    // wave wv owns tokens c*256 + wv*32 + l31 for each chunk c.
    for (int c = 0; c < 2; ++c) {
        f32x16 accQ = z32, accK = z32, accV = z32;
        for (int p = 0; p < 8; ++p) {           // 32 k-cols per pass
            __syncthreads();
            // stage x[256 tok][32 k] f32 -> bf16 LDS (4 iters, 8 lanes/token)
            #pragma unroll
            for (int it = 0; it < 4; ++it) {
                const int tok = it * 64 + wv * 8 + (lane >> 3);
                const int cc  = (lane & 7) * 4;
                float4 v = *(const float4*)&x[((size_t)(bt * NTOK + c * 256 + tok)) * DIM
                                              + p * 32 + cc];
                uint2 w;
                w.x = (u32)f2bf(v.x) | ((u32)f2bf(v.y) << 16);
                w.y = (u32)f2bf(v.z) | ((u32)f2bf(v.w) << 16);
                *(uint2*)&XP[tok * 40 + cc] = w;
            }
            __syncthreads();
            #pragma unroll
            for (int ks = 0; ks < 2; ++ks) {
                const int kg = p * 32 + ks * 16 + hi * 8;   // global k 0..255
                short8 xf = *(const short8*)&XP[(wv * 32 + l31) * 40 + ks * 16 + hi * 8];
                short8 wq = *(const short8*)&Wt[(size_t)0 * 65536 + (size_t)(h * 32 + l31) * DIM + kg];
                short8 wk = *(const short8*)&Wt[(size_t)1 * 65536 + (size_t)(h * 32 + l31) * DIM + kg];
                short8 wvv= *(const short8*)&Wt[(size_t)2 * 65536 + (size_t)(h * 32 + l31) * DIM + kg];
                accQ = MFMA32(wq, xf, accQ);   // D: col=token(l31), row=dim
                accK = MFMA32(wk, xf, accK);
                accV = MFMA32(xf, wvv, accV);  // D: col=dim(l31),  row=token
            }
        }
        // ---- chunk epilogue ----
        // Q -> gQ [token][dim] (scaled); dims d(r) = (r&3)+8*(r>>2)+4*hi
        #pragma unroll
        for (int rq = 0; rq < 4; ++rq) {
            uint2 w;
            w.x = pack_trunc(accQ[4*rq+0] * QSCALE, accQ[4*rq+1] * QSCALE);
            w.y = pack_trunc(accQ[4*rq+2] * QSCALE, accQ[4*rq+3] * QSCALE);
            *(uint2*)&gQ[(c * 256 + wv * 32 + l31) * 32 + 8 * rq + 4 * hi] = w;
        }
        // K -> frag-order: elem = g*1024 + key_in_g*8 + oct*256 + j
        // (key = wv*32 + l31 -> g=wv; dim = 8rq+4hi+0..3 -> oct=rq)
        #pragma unroll
        for (int rq = 0; rq < 4; ++rq) {
            uint2 w;
            w.x = pack_trunc(accK[4*rq+0], accK[4*rq+1]);
            w.y = pack_trunc(accK[4*rq+2], accK[4*rq+3]);
            const int off = wv * 1024 + l31 * 8 + rq * 256 + 4 * hi;
            if (c == 0) *(uint2*)&KlsF[off] = w;
            else        *(uint2*)&gK[off]   = w;
        }
        // V -> frag-order V^T: elem = kt*1024 + ko*256 + dim*8 + j
        // (dim = l31; key = wv*32 + 8rq+4hi+0..3 -> kt=wv, ko=rq)
        #pragma unroll
        for (int rq = 0; rq < 4; ++rq) {
            uint2 w;
            w.x = pack_trunc(accV[4*rq+0], accV[4*rq+1]);
            w.y = pack_trunc(accV[4*rq+2], accV[4*rq+3]);
            const int off = wv * 1024 + rq * 256 + l31 * 8 + 4 * hi;
            if (c == 0) *(uint2*)&VtF[off] = w;
            else        *(uint2*)&gV[off]  = w;
        }
    }
    __syncthreads();   // K/V(0) LDS + gQ visible to all waves

    // =================== Phase 2: attention ===================
    // wave wv: 64 q rows = 4 tiles of 16: q = wv*64 + qbi*16 + q16
    short8 qv[4];
    #pragma unroll
    for (int qbi = 0; qbi < 4; ++qbi)
        qv[qbi] = *(const short8*)&gQ[(wv * 64 + qbi * 16 + q16) * 32 + quad * 8];

    const short8 z8 = {0,0,0,0,0,0,0,0};
    const f32x4  z4 = {0.f,0.f,0.f,0.f};
    f32x4 o1lo[4], o1hi[4], o2lo[4], o2hi[4];
    float l1[4] = {0.f,0.f,0.f,0.f}, l2[4] = {0.f,0.f,0.f,0.f};
    #pragma unroll
    for (int qbi = 0; qbi < 4; ++qbi) {
        o1lo[qbi] = z4; o1hi[qbi] = z4; o2lo[qbi] = z4; o2hi[qbi] = z4;
    }

    u16* P1 = &XP[wv * 1152];        // [16 q][36 keys] dual-P per wave
    u16* P2 = P1 + 576;

    for (int kc = 0; kc < 2; ++kc) {
        if (kc) {
            // reload chunk-1 K/V from scratch (linear, L2-hot)
            __syncthreads();
            #pragma unroll
            for (int i = 0; i < 2; ++i) {
                ((uint4*)KlsF)[tid + i * 512] = ((const uint4*)gK)[tid + i * 512];
                ((uint4*)VtF)[tid + i * 512]  = ((const uint4*)gV)[tid + i * 512];
            }
            __syncthreads();
        }
        for (int kt = 0; kt < 8; ++kt) {   // 32-key tiles
            // K frags (A-op, m=key): full 32 dims, per 16-key sub
            const short8 kf0 = *(const short8*)&KlsF[kt * 1024 + (0 * 16 + q16) * 8 + quad * 256];
            const short8 kf1 = *(const short8*)&KlsF[kt * 1024 + (1 * 16 + q16) * 8 + quad * 256];
            // V frags (B-op, n=dim): lo dims 0..15, hi dims 16..31
            const short8 vlo = *(const short8*)&VtF[kt * 1024 + quad * 256 + q16 * 8];
            const short8 vhi = *(const short8*)&VtF[kt * 1024 + quad * 256 + (16 + q16) * 8];

            #pragma unroll
            for (int qbi = 0; qbi < 4; ++qbi) {
                const short8 A1 = (lane < 32) ? qv[qbi] : z8;  // Q1: dims 0..15
                const short8 A2 = (lane < 32) ? z8 : qv[qbi];  // Q2: dims 16..31
                #pragma unroll
                for (int sub = 0; sub < 2; ++sub) {
                    const short8 kf = sub ? kf1 : kf0;
                    f32x4 s1 = MFMA16(kf, A1, z4);   // D[key=quad*4+r][q=q16]
                    f32x4 s2 = MFMA16(kf, A2, z4);
                    float p0 = fexp2(s1[0]), p1 = fexp2(s1[1]);
                    float p2 = fexp2(s1[2]), p3 = fexp2(s1[3]);
                    l1[qbi] += (p0 + p1) + (p2 + p3);
                    uint2 w1; w1.x = pack_trunc(p0, p1); w1.y = pack_trunc(p2, p3);
                    *(uint2*)&P1[q16 * 36 + sub * 16 + quad * 4] = w1;
                    float r0 = fexp2(s2[0]), r1 = fexp2(s2[1]);
                    float r2 = fexp2(s2[2]), r3 = fexp2(s2[3]);
                    l2[qbi] += (r0 + r1) + (r2 + r3);
                    uint2 w2; w2.x = pack_trunc(r0, r1); w2.y = pack_trunc(r2, r3);
                    *(uint2*)&P2[q16 * 36 + sub * 16 + quad * 4] = w2;
                }
                const short8 pf1 = ldb64x2(&P1[q16 * 36 + quad * 8]);
                const short8 pf2 = ldb64x2(&P2[q16 * 36 + quad * 8]);
                o1lo[qbi] = MFMA16(pf1, vlo, o1lo[qbi]);
                o1hi[qbi] = MFMA16(pf1, vhi, o1hi[qbi]);
                o2lo[qbi] = MFMA16(pf2, vlo, o2lo[qbi]);
                o2hi[qbi] = MFMA16(pf2, vhi, o2hi[qbi]);
            }
        }
    }

    // =================== epilogue ===================
    const float g_lo = gamma[q16],  g_hi = gamma[16 + q16];
    const float b_lo = beta[q16],   b_hi = beta[16 + q16];

    #pragma unroll
    for (int qbi = 0; qbi < 4; ++qbi) {
        float a = l1[qbi], b = l2[qbi];
        a += __shfl_xor(a, 16); a += __shfl_xor(a, 32);
        b += __shfl_xor(b, 16); b += __shfl_xor(b, 32);
        const float inv1 = 1.0f / a;   // valid for q = q16
        const float inv2 = 1.0f / b;
        #pragma unroll
        for (int r = 0; r < 4; ++r) {
            const float i1 = __shfl(inv1, quad * 4 + r);
            const float i2 = __shfl(inv2, quad * 4 + r);
            const float ylo = o1lo[qbi][r] * i1 - lam * (o2lo[qbi][r] * i2);
            const float yhi = o1hi[qbi][r] * i1 - lam * (o2hi[qbi][r] * i2);

            float s  = ylo + yhi;
            float s2 = ylo * ylo + yhi * yhi;
            #pragma unroll
            for (int off = 1; off < 16; off <<= 1) {
                s  += __shfl_xor(s,  off);
                s2 += __shfl_xor(s2, off);
            }
            const float mu   = s * (1.0f / 32.0f);
            const float var  = s2 * (1.0f / 32.0f) - mu * mu;
            const float rstd = rsqrtf(var + LN_EPS);

            const int row = bt * NTOK + wv * 64 + qbi * 16 + quad * 4 + r;
            float* orow = out + (size_t)row * HID + h * 32;
            orow[q16]      = ((ylo - mu) * rstd * g_lo + b_lo) * ONE_MINUS_LI;
            orow[16 + q16] = ((yhi - mu) * rstd * g_hi + b_hi) * ONE_MINUS_LI;
        }
    }
}

// ---------------------------------------------------------------------------
extern "C" void kernel_launch(void* const* d_in, const int* in_sizes, int n_in,
                              void* d_out, int out_size, void* d_ws, size_t ws_size,
                              hipStream_t stream) {
    const float* x   = (const float*)d_in[0];
    const float* Wq  = (const float*)d_in[1];
    const float* Wk  = (const float*)d_in[2];
    const float* Wv  = (const float*)d_in[3];
    const float* lq1 = (const float*)d_in[4];
    const float* lk1 = (const float*)d_in[5];
    const float* lq2 = (const float*)d_in[6];
    const float* lk2 = (const float*)d_in[7];
    const float* gam = (const float*)d_in[8];
    const float* bet = (const float*)d_in[9];
    float* out = (float*)d_out;

    u16* ws = (u16*)d_ws;
    u16* Wt = ws;                     // 3 * 65536 u16
    u16* gscratch = Wt + 3 * 65536;   // 256 blocks * 32768 u16

    hipLaunchKernelGGL(prep_w, dim3(4, 4, 3), dim3(256), 0, stream, Wq, Wk, Wv, Wt);
    hipLaunchKernelGGL(fused_kernel, dim3(32, 8), dim3(512), 0, stream,
                       x, Wt, gscratch, lq1, lk1, lq2, lk2, gam, bet, out);
}